// Round 4
// baseline (207.908 us; speedup 1.0000x reference)
//
#include <hip/hip_runtime.h>
#include <math.h>

// RansacRouting: B=32, I=1152, O=10, D=16, H=10, S=922
// Fused single kernel: one block per (b,o,h). Each block builds its own
// hypothesis bitmask, computes Mu via predicated scan, computes fp64 loss
// via second scan, then participates in a per-(b,o) argmin epilogue:
// packed atomicMin + arrival counter; the 10th (last) block writes out.

#define B_    32
#define I_    1152
#define O_    10
#define D_    16
#define H_    10
#define S_    922
#define MASKW 36      // 1152/32
#define NT    256

// ---- wave64 sum via DPP (VALU pipe) -- result valid in lane 63 ----
template <int CTRL, int ROWM>
static __device__ __forceinline__ float dpp_f(float v) {
    return __int_as_float(__builtin_amdgcn_update_dpp(
        0, __float_as_int(v), CTRL, ROWM, 0xf, true));
}
static __device__ __forceinline__ float wave_sum_f32(float v) {
    v += dpp_f<0x111, 0xf>(v);   // row_shr:1
    v += dpp_f<0x112, 0xf>(v);   // row_shr:2
    v += dpp_f<0x114, 0xf>(v);   // row_shr:4
    v += dpp_f<0x118, 0xf>(v);   // row_shr:8
    v += dpp_f<0x142, 0xa>(v);   // row_bcast15
    v += dpp_f<0x143, 0xc>(v);   // row_bcast31
    return v;
}
template <int CTRL, int ROWM>
static __device__ __forceinline__ double dpp_d(double v) {
    long long x = __double_as_longlong(v);
    int lo = (int)(unsigned)(x & 0xffffffffLL);
    int hi = (int)(x >> 32);
    lo = __builtin_amdgcn_update_dpp(0, lo, CTRL, ROWM, 0xf, true);
    hi = __builtin_amdgcn_update_dpp(0, hi, CTRL, ROWM, 0xf, true);
    return __longlong_as_double((long long)(unsigned)lo | ((long long)hi << 32));
}
static __device__ __forceinline__ double wave_sum_f64(double v) {
    v += dpp_d<0x111, 0xf>(v);
    v += dpp_d<0x112, 0xf>(v);
    v += dpp_d<0x114, 0xf>(v);
    v += dpp_d<0x118, 0xf>(v);
    v += dpp_d<0x142, 0xa>(v);
    v += dpp_d<0x143, 0xc>(v);
    return v;
}

__global__ __launch_bounds__(NT) void ransac_fused(
    const float* __restrict__ up,               // [B,I,O,D]
    const int*   __restrict__ sidx,             // [B,S,O,H]
    float*       __restrict__ muw,              // [B*O, H, D] ws
    unsigned long long* __restrict__ winner,    // [B*O] ws, init 0xFF..
    int*         __restrict__ counter,          // [B*O] ws, init -1
    float*       __restrict__ out)              // [B,O,D]
{
    __shared__ unsigned mask[MASKW];
    __shared__ float    red[4][17];
    __shared__ float    mus[17];    // [0..15]=num, [16]=den
    __shared__ double   lred[4];
    __shared__ int      lastf;

    // XCD swizzle: the 100 (o,h)-blocks of one b share an XCD (u[b]=737 KB in L2)
    const int g   = blockIdx.x;
    const int xcd = g & 7;
    const int r   = g >> 3;             // [0,400)
    const int bhi = r / 100;            // [0,4)
    const int rem = r - 100 * bhi;      // [0,100)
    const int o   = rem / 10;
    const int h   = rem - 10 * o;
    const int b   = bhi * 8 + xcd;
    const int bo  = b * O_ + o;

    const int tid  = threadIdx.x;
    const int lane = tid & 63;
    const int wv   = tid >> 6;

    if (tid < MASKW) mask[tid] = 0u;
    __syncthreads();

    // --- A: build hypothesis bitmask (922 scattered L2 loads) ---
    const int* sb = sidx + (size_t)b * (S_ * O_ * H_) + o * H_ + h;
    for (int s = tid; s < S_; s += NT) {
        int idx = sb[(size_t)s * (O_ * H_)];
        atomicOr(&mask[idx >> 5], 1u << (idx & 31));
    }
    __syncthreads();

    // --- B: predicated scan -> num[16], den ---
    const float* ub = up + ((size_t)b * I_ * O_ + o) * D_;
    float acc[17];
    #pragma unroll
    for (int d = 0; d < 17; ++d) acc[d] = 0.f;
    for (int i = tid; i < I_; i += NT) {
        unsigned bit = (mask[i >> 5] >> (i & 31)) & 1u;
        const float4* p = (const float4*)(ub + (size_t)i * (O_ * D_));
        float4 q0 = p[0], q1 = p[1], q2 = p[2], q3 = p[3];
        float s = q0.x*q0.x + q0.y*q0.y + q0.z*q0.z + q0.w*q0.w
                + q1.x*q1.x + q1.y*q1.y + q1.z*q1.z + q1.w*q1.w
                + q2.x*q2.x + q2.y*q2.y + q2.z*q2.z + q2.w*q2.w
                + q3.x*q3.x + q3.y*q3.y + q3.z*q3.z + q3.w*q3.w;
        float vn = sqrtf(s);
        float w  = bit ? vn : 0.f;     // v_cndmask, no divergence
        acc[ 0] = fmaf(w, q0.x, acc[ 0]); acc[ 1] = fmaf(w, q0.y, acc[ 1]);
        acc[ 2] = fmaf(w, q0.z, acc[ 2]); acc[ 3] = fmaf(w, q0.w, acc[ 3]);
        acc[ 4] = fmaf(w, q1.x, acc[ 4]); acc[ 5] = fmaf(w, q1.y, acc[ 5]);
        acc[ 6] = fmaf(w, q1.z, acc[ 6]); acc[ 7] = fmaf(w, q1.w, acc[ 7]);
        acc[ 8] = fmaf(w, q2.x, acc[ 8]); acc[ 9] = fmaf(w, q2.y, acc[ 9]);
        acc[10] = fmaf(w, q2.z, acc[10]); acc[11] = fmaf(w, q2.w, acc[11]);
        acc[12] = fmaf(w, q3.x, acc[12]); acc[13] = fmaf(w, q3.y, acc[13]);
        acc[14] = fmaf(w, q3.z, acc[14]); acc[15] = fmaf(w, q3.w, acc[15]);
        acc[16] += w;
    }
    #pragma unroll
    for (int d = 0; d < 17; ++d) acc[d] = wave_sum_f32(acc[d]);
    if (lane == 63) {
        #pragma unroll
        for (int d = 0; d < 17; ++d) red[wv][d] = acc[d];
    }
    __syncthreads();
    if (tid < 17)
        mus[tid] = red[0][tid] + red[1][tid] + red[2][tid] + red[3][tid];
    __syncthreads();

    // --- C: loss scan (all threads hold Mu in registers) ---
    const float rden = 1.f / mus[16];
    float mu[D_];
    #pragma unroll
    for (int d = 0; d < D_; ++d) mu[d] = mus[d] * rden;
    float musq = 0.f;
    #pragma unroll
    for (int d = 0; d < D_; ++d) musq = fmaf(mu[d], mu[d], musq);

    double lacc = 0.0;
    for (int i = tid; i < I_; i += NT) {
        const float4* p = (const float4*)(ub + (size_t)i * (O_ * D_));
        float4 q0 = p[0], q1 = p[1], q2 = p[2], q3 = p[3];
        float uq[D_] = {q0.x,q0.y,q0.z,q0.w, q1.x,q1.y,q1.z,q1.w,
                        q2.x,q2.y,q2.z,q2.w, q3.x,q3.y,q3.z,q3.w};
        float usq = 0.f, dot = 0.f;
        #pragma unroll
        for (int d = 0; d < D_; ++d) {
            usq = fmaf(uq[d], uq[d], usq);
            dot = fmaf(uq[d], mu[d], dot);
        }
        float d2 = fmaf(-2.f, dot, usq + musq);
        lacc += (double)sqrtf(fmaxf(d2, 0.f));
    }
    lacc = wave_sum_f64(lacc);
    if (lane == 63) lred[wv] = lacc;

    // --- publish Mu (agent-scope stores, coherent across XCDs) ---
    if (tid < D_)
        __hip_atomic_store(&muw[((size_t)bo * H_ + h) * D_ + tid],
                           mus[tid] * rden,
                           __ATOMIC_RELAXED, __HIP_MEMORY_SCOPE_AGENT);
    __syncthreads();   // drains all stores (vmcnt(0) before barrier)

    if (tid == 0) {
        double L = lred[0] + lred[1] + lred[2] + lred[3];
        // positive double -> monotone u64; low 4 bits carry h (ties -> smaller h,
        // matching np.argmin first-min tie-break)
        unsigned long long pk =
            (((unsigned long long)__double_as_longlong(L)) & ~0xFULL) | (unsigned)h;
        atomicMin(&winner[bo], pk);
        int old = __hip_atomic_fetch_add(&counter[bo], 1,
                                         __ATOMIC_ACQ_REL, __HIP_MEMORY_SCOPE_AGENT);
        lastf = (old == 8);   // counter init -1; 10th arrival sees 8
    }
    __syncthreads();

    // --- last-arriving block of this (b,o) writes the winner's Mu ---
    if (lastf && tid < D_) {
        unsigned long long w = __hip_atomic_load(&winner[bo],
                                __ATOMIC_ACQUIRE, __HIP_MEMORY_SCOPE_AGENT);
        int hs = (int)(w & 0xF);
        float v = __hip_atomic_load(&muw[((size_t)bo * H_ + hs) * D_ + tid],
                                    __ATOMIC_RELAXED, __HIP_MEMORY_SCOPE_AGENT);
        out[(size_t)bo * D_ + tid] = v;
    }
}

extern "C" void kernel_launch(void* const* d_in, const int* in_sizes, int n_in,
                              void* d_out, int out_size, void* d_ws, size_t ws_size,
                              hipStream_t stream) {
    const float* up   = (const float*)d_in[0];
    const int*   sidx = (const int*)d_in[1];
    float*       out  = (float*)d_out;

    // ws layout: muw [320*10*16 f32] | winner [320 u64] | counter [320 i32]
    float* muw = (float*)d_ws;
    unsigned long long* winner = (unsigned long long*)((char*)d_ws + 204800);
    int* counter = (int*)((char*)d_ws + 204800 + 2560);

    // init winner -> 0xFF.. (= +inf for packed positive doubles), counter -> -1
    hipMemsetAsync((char*)d_ws + 204800, 0xFF, 2560 + 1280, stream);

    ransac_fused<<<B_ * O_ * H_, NT, 0, stream>>>(up, sidx, muw, winner, counter, out);
}

// Round 5
// 142.969 us; speedup vs baseline: 1.4542x; 1.4542x over previous
//
#include <hip/hip_runtime.h>
#include <math.h>

// RansacRouting: B=32, I=1152, O=10, D=16, H=10, S=922
// R5: transpose-first pipeline (all hot loops coalesced).
//   K0: 1600 blocks transpose u[b,i,o,:] -> ut[bo][d][i] (via LDS) +
//       320 blocks build all 10 bitmasks per (b,o) -> maskw
//   K2: 1600 blocks, one per (b,o,h-pair): coalesced num-scan + loss-scan,
//       2 hypotheses share loads; packed atomicMin argmin; last block writes.

#define B_    32
#define I_    1152
#define O_    10
#define D_    16
#define H_    10
#define S_    922
#define MASKW 36

// ws offsets (bytes)
#define UT_OFF  0u                       // float ut[320][16][1152]  = 23,592,960
#define MK_OFF  23592960u                // u32  maskw[320][10][36]  =    460,800
#define MU_OFF  24053760u                // float muw[320][10][16]   =    204,800
#define WIN_OFF 24258560u                // u64  winner[320]         =      2,560
#define CNT_OFF 24261120u                // i32  counter[320]        =      1,280

// ---- wave64 sum via DPP (VALU pipe) -- result valid in lane 63 ----
template <int CTRL, int ROWM>
static __device__ __forceinline__ float dpp_f(float v) {
    return __int_as_float(__builtin_amdgcn_update_dpp(
        0, __float_as_int(v), CTRL, ROWM, 0xf, true));
}
static __device__ __forceinline__ float wave_sum_f32(float v) {
    v += dpp_f<0x111, 0xf>(v);
    v += dpp_f<0x112, 0xf>(v);
    v += dpp_f<0x114, 0xf>(v);
    v += dpp_f<0x118, 0xf>(v);
    v += dpp_f<0x142, 0xa>(v);
    v += dpp_f<0x143, 0xc>(v);
    return v;
}
template <int CTRL, int ROWM>
static __device__ __forceinline__ double dpp_d(double v) {
    long long x = __double_as_longlong(v);
    int lo = (int)(unsigned)(x & 0xffffffffLL);
    int hi = (int)(x >> 32);
    lo = __builtin_amdgcn_update_dpp(0, lo, CTRL, ROWM, 0xf, true);
    hi = __builtin_amdgcn_update_dpp(0, hi, CTRL, ROWM, 0xf, true);
    return __longlong_as_double((long long)(unsigned)lo | ((long long)hi << 32));
}
static __device__ __forceinline__ double wave_sum_f64(double v) {
    v += dpp_d<0x111, 0xf>(v);
    v += dpp_d<0x112, 0xf>(v);
    v += dpp_d<0x114, 0xf>(v);
    v += dpp_d<0x118, 0xf>(v);
    v += dpp_d<0x142, 0xa>(v);
    v += dpp_d<0x143, 0xc>(v);
    return v;
}

// =================== K0: transpose + mask build ===================
__global__ __launch_bounds__(256) void k0_prep(
    const float* __restrict__ up,      // [B,I,O,D]
    const int*   __restrict__ sidx,    // [B,S,O,H]
    float*       __restrict__ ut,      // [320][16][1152]
    unsigned*    __restrict__ maskw)   // [320][10][36]
{
    __shared__ float    lt[16][260];   // 260 pad: float4-aligned, conflict-free
    __shared__ unsigned mask[H_][MASKW];

    const int g   = blockIdx.x;
    const int tid = threadIdx.x;

    if (g < 1600) {
        // ---- transpose chunk: bo = g%320, chunk c = g/320 (rows c*256..) ----
        const int bo = g % 320;
        const int c  = g / 320;
        const int b  = bo / O_;
        const int o  = bo - b * O_;
        const int i0 = c * 256;
        const int n  = (i0 + 256 <= I_) ? 256 : (I_ - i0);   // 256 or 128

        if (tid < n) {
            const int i = i0 + tid;
            const float4* p = (const float4*)(up + (((size_t)b * I_ + i) * O_ + o) * D_);
            float4 q0 = p[0], q1 = p[1], q2 = p[2], q3 = p[3];
            lt[ 0][tid]=q0.x; lt[ 1][tid]=q0.y; lt[ 2][tid]=q0.z; lt[ 3][tid]=q0.w;
            lt[ 4][tid]=q1.x; lt[ 5][tid]=q1.y; lt[ 6][tid]=q1.z; lt[ 7][tid]=q1.w;
            lt[ 8][tid]=q2.x; lt[ 9][tid]=q2.y; lt[10][tid]=q2.z; lt[11][tid]=q2.w;
            lt[12][tid]=q3.x; lt[13][tid]=q3.y; lt[14][tid]=q3.z; lt[15][tid]=q3.w;
        }
        __syncthreads();

        const int sh   = (n == 256) ? 6 : 5;          // nf4 = 64 or 32
        const int nf4  = 1 << sh;
        float* base = ut + (size_t)bo * (D_ * I_);
        for (int j = tid; j < (nf4 << 4); j += 256) {
            int d = j >> sh;
            int t = j & (nf4 - 1);
            float4 v = *(const float4*)&lt[d][4 * t];
            *(float4*)&base[(size_t)d * I_ + i0 + 4 * t] = v;
        }
    } else {
        // ---- mask block: one per (b,o) ----
        const int m  = g - 1600;
        const int b  = m / O_;
        const int o  = m - b * O_;
        for (int j = tid; j < H_ * MASKW; j += 256) ((unsigned*)mask)[j] = 0u;
        __syncthreads();
        const int* sb = sidx + (size_t)b * (S_ * O_ * H_) + o * H_;
        for (int j = tid; j < S_ * H_; j += 256) {
            int s = j / H_;
            int h = j - s * H_;
            int idx = sb[s * (O_ * H_) + h];
            atomicOr(&mask[h][idx >> 5], 1u << (idx & 31));
        }
        __syncthreads();
        unsigned* mo = maskw + (size_t)m * (H_ * MASKW);
        for (int j = tid; j < H_ * MASKW; j += 256)
            mo[j] = ((unsigned*)mask)[j];
    }
}

// =================== K2: per-(b,o,h-pair) num + loss + argmin ===================
__global__ __launch_bounds__(256) void k2_main(
    const float* __restrict__ ut,
    const unsigned* __restrict__ maskw,
    float* __restrict__ muw,
    unsigned long long* __restrict__ winner,
    int* __restrict__ counter,
    float* __restrict__ out)
{
    __shared__ unsigned maskAB[72];
    __shared__ float    red[2][4][17];
    __shared__ float    mus[2][17];
    __shared__ double   lred[2][4];
    __shared__ int      lastf;

    // XCD swizzle: all 50 (o,hp) blocks of one b share an XCD
    const int g   = blockIdx.x;            // [0,1600)
    const int xcd = g & 7;
    const int r   = g >> 3;                // [0,200)
    const int bhi = r / 50;
    const int rem = r - 50 * bhi;          // [0,50)
    const int o   = rem / 5;
    const int hp  = rem - 5 * o;
    const int b   = bhi * 8 + xcd;
    const int bo  = b * O_ + o;
    const int h0  = hp * 2;

    const int tid  = threadIdx.x;
    const int lane = tid & 63;
    const int wv   = tid >> 6;

    if (tid < 72) maskAB[tid] = maskw[(size_t)bo * (H_ * MASKW) + h0 * MASKW + tid];
    __syncthreads();

    const float* base = ut + (size_t)bo * (D_ * I_);

    // ---- pass 1: masked num/den for both hypotheses (coalesced lane=i) ----
    float acc[2][17];
    #pragma unroll
    for (int p = 0; p < 2; ++p)
        #pragma unroll
        for (int d = 0; d < 17; ++d) acc[p][d] = 0.f;

    for (int i = tid; i < I_; i += 256) {
        float q[D_];
        #pragma unroll
        for (int d = 0; d < D_; ++d) q[d] = base[(size_t)d * I_ + i];
        float usq = 0.f;
        #pragma unroll
        for (int d = 0; d < D_; ++d) usq = fmaf(q[d], q[d], usq);
        float vn = sqrtf(usq);
        #pragma unroll
        for (int p = 0; p < 2; ++p) {
            unsigned bit = (maskAB[p * MASKW + (i >> 5)] >> (i & 31)) & 1u;
            float w = bit ? vn : 0.f;
            acc[p][16] += w;
            #pragma unroll
            for (int d = 0; d < D_; ++d) acc[p][d] = fmaf(w, q[d], acc[p][d]);
        }
    }
    #pragma unroll
    for (int p = 0; p < 2; ++p)
        #pragma unroll
        for (int d = 0; d < 17; ++d) acc[p][d] = wave_sum_f32(acc[p][d]);
    if (lane == 63) {
        #pragma unroll
        for (int p = 0; p < 2; ++p)
            #pragma unroll
            for (int d = 0; d < 17; ++d) red[p][wv][d] = acc[p][d];
    }
    __syncthreads();
    if (tid < 34) {
        int p = tid / 17, d = tid - 17 * p;
        mus[p][d] = red[p][0][d] + red[p][1][d] + red[p][2][d] + red[p][3][d];
    }
    __syncthreads();

    // ---- pass 2: fp64 loss for both hypotheses ----
    float rden[2] = {1.f / mus[0][16], 1.f / mus[1][16]};
    float mu[2][D_], musq[2];
    #pragma unroll
    for (int p = 0; p < 2; ++p) {
        float s = 0.f;
        #pragma unroll
        for (int d = 0; d < D_; ++d) {
            mu[p][d] = mus[p][d] * rden[p];
            s = fmaf(mu[p][d], mu[p][d], s);
        }
        musq[p] = s;
    }
    double lacc[2] = {0.0, 0.0};
    for (int i = tid; i < I_; i += 256) {
        float q[D_];
        #pragma unroll
        for (int d = 0; d < D_; ++d) q[d] = base[(size_t)d * I_ + i];
        float usq = 0.f;
        #pragma unroll
        for (int d = 0; d < D_; ++d) usq = fmaf(q[d], q[d], usq);
        #pragma unroll
        for (int p = 0; p < 2; ++p) {
            float dot = 0.f;
            #pragma unroll
            for (int d = 0; d < D_; ++d) dot = fmaf(q[d], mu[p][d], dot);
            float d2 = fmaf(-2.f, dot, usq + musq[p]);
            lacc[p] += (double)sqrtf(fmaxf(d2, 0.f));
        }
    }
    #pragma unroll
    for (int p = 0; p < 2; ++p) lacc[p] = wave_sum_f64(lacc[p]);
    if (lane == 63) { lred[0][wv] = lacc[0]; lred[1][wv] = lacc[1]; }

    // ---- publish Mu (agent scope) ----
    if (tid < 32) {
        int p = tid >> 4, d = tid & 15;
        __hip_atomic_store(&muw[((size_t)bo * H_ + h0 + p) * D_ + d],
                           mus[p][d] * rden[p],
                           __ATOMIC_RELAXED, __HIP_MEMORY_SCOPE_AGENT);
    }
    __syncthreads();   // drains stores + lred visible

    if (tid == 0) {
        #pragma unroll
        for (int p = 0; p < 2; ++p) {
            double L = lred[p][0] + lred[p][1] + lred[p][2] + lred[p][3];
            unsigned long long pk =
                (((unsigned long long)__double_as_longlong(L)) & ~0xFULL)
                | (unsigned)(h0 + p);
            atomicMin(&winner[bo], pk);
        }
        int old = __hip_atomic_fetch_add(&counter[bo], 1,
                                         __ATOMIC_ACQ_REL, __HIP_MEMORY_SCOPE_AGENT);
        lastf = (old == 3);   // counter init -1; 5th arrival sees 3
    }
    __syncthreads();

    if (lastf && tid < D_) {
        unsigned long long w = __hip_atomic_load(&winner[bo],
                                __ATOMIC_ACQUIRE, __HIP_MEMORY_SCOPE_AGENT);
        int hs = (int)(w & 0xF);
        float v = __hip_atomic_load(&muw[((size_t)bo * H_ + hs) * D_ + tid],
                                    __ATOMIC_RELAXED, __HIP_MEMORY_SCOPE_AGENT);
        out[(size_t)bo * D_ + tid] = v;
    }
}

extern "C" void kernel_launch(void* const* d_in, const int* in_sizes, int n_in,
                              void* d_out, int out_size, void* d_ws, size_t ws_size,
                              hipStream_t stream) {
    const float* up   = (const float*)d_in[0];
    const int*   sidx = (const int*)d_in[1];
    float*       out  = (float*)d_out;

    float*    ut    = (float*)((char*)d_ws + UT_OFF);
    unsigned* maskw = (unsigned*)((char*)d_ws + MK_OFF);
    float*    muw   = (float*)((char*)d_ws + MU_OFF);
    unsigned long long* winner = (unsigned long long*)((char*)d_ws + WIN_OFF);
    int*      counter = (int*)((char*)d_ws + CNT_OFF);

    // winner -> 0xFF.. (> any packed positive double), counter -> -1
    hipMemsetAsync((char*)d_ws + WIN_OFF, 0xFF, 2560 + 1280, stream);

    k0_prep<<<1920, 256, 0, stream>>>(up, sidx, ut, maskw);
    k2_main<<<1600, 256, 0, stream>>>(ut, maskw, muw, winner, counter, out);
}

// Round 6
// 115.286 us; speedup vs baseline: 1.8034x; 1.2401x over previous
//
#include <hip/hip_runtime.h>
#include <math.h>

// RansacRouting: B=32, I=1152, O=10, D=16, H=10, S=922
// R6: single fused kernel, ONE sweep of u. One block per (b,o), 512 threads.
// Each thread holds 2-3 u-rows in registers. Per-row 10-bit hypothesis
// membership via LDS atomicOr. 5 h-pair Mu phases (DPP+LDS reduce), loss
// phase from registers, in-block argmin, direct output. No workspace.

#define B_ 32
#define I_ 1152
#define O_ 10
#define H_ 10
#define S_ 922
#define D_ 16
#define NT 512

// ---- wave64 sum via DPP (VALU pipe) -- result valid in lane 63 ----
template <int CTRL, int ROWM>
static __device__ __forceinline__ float dpp_f(float v) {
    return __int_as_float(__builtin_amdgcn_update_dpp(
        0, __float_as_int(v), CTRL, ROWM, 0xf, true));
}
static __device__ __forceinline__ float wave_sum_f32(float v) {
    v += dpp_f<0x111, 0xf>(v);   // row_shr:1
    v += dpp_f<0x112, 0xf>(v);   // row_shr:2
    v += dpp_f<0x114, 0xf>(v);   // row_shr:4
    v += dpp_f<0x118, 0xf>(v);   // row_shr:8
    v += dpp_f<0x142, 0xa>(v);   // row_bcast15
    v += dpp_f<0x143, 0xc>(v);   // row_bcast31
    return v;
}
template <int CTRL, int ROWM>
static __device__ __forceinline__ double dpp_d(double v) {
    long long x = __double_as_longlong(v);
    int lo = (int)(unsigned)(x & 0xffffffffLL);
    int hi = (int)(x >> 32);
    lo = __builtin_amdgcn_update_dpp(0, lo, CTRL, ROWM, 0xf, true);
    hi = __builtin_amdgcn_update_dpp(0, hi, CTRL, ROWM, 0xf, true);
    return __longlong_as_double((long long)(unsigned)lo | ((long long)hi << 32));
}
static __device__ __forceinline__ double wave_sum_f64(double v) {
    v += dpp_d<0x111, 0xf>(v);
    v += dpp_d<0x112, 0xf>(v);
    v += dpp_d<0x114, 0xf>(v);
    v += dpp_d<0x118, 0xf>(v);
    v += dpp_d<0x142, 0xa>(v);
    v += dpp_d<0x143, 0xc>(v);
    return v;
}

__global__ __launch_bounds__(NT) void ransac_one(
    const float* __restrict__ up,      // [B,I,O,D]
    const int*   __restrict__ sidx,    // [B,S,O,H]
    float*       __restrict__ out)     // [B,O,D]
{
    __shared__ unsigned rowmask[I_];       // 4608 B: 10-bit membership per row
    __shared__ float    red[8][34];        // per-wave phase partials
    __shared__ float    muL[H_][D_];       // all 10 means
    __shared__ double   lred[H_][8];
    __shared__ double   losses[H_];
    __shared__ int      hstar;

    // XCD swizzle: 10 o-blocks of one b share an XCD (up[b]+sidx[b] ~1.1MB in L2)
    const int g   = blockIdx.x;
    const int xcd = g & 7, r = g >> 3;     // r in [0,40)
    const int bhi = r / O_;
    const int o   = r - bhi * O_;
    const int b   = bhi * 8 + xcd;
    const int bo  = b * O_ + o;

    const int tid  = threadIdx.x;
    const int lane = tid & 63;
    const int wv   = tid >> 6;
    const bool has3 = (tid < 128);         // waves 0,1 own a third row (uniform/wave)

    for (int j = tid; j < I_; j += NT) rowmask[j] = 0u;

    // --- load this thread's rows into registers (rows are 64B contiguous) ---
    const float* ub = up + (((size_t)b * I_) * O_ + o) * D_;
    float u0[D_], u1[D_], u2[D_];
    {
        const float4* p = (const float4*)(ub + (size_t)tid * (O_ * D_));
        float4 a = p[0], bq = p[1], c = p[2], dq = p[3];
        u0[0]=a.x; u0[1]=a.y; u0[2]=a.z; u0[3]=a.w;
        u0[4]=bq.x; u0[5]=bq.y; u0[6]=bq.z; u0[7]=bq.w;
        u0[8]=c.x; u0[9]=c.y; u0[10]=c.z; u0[11]=c.w;
        u0[12]=dq.x; u0[13]=dq.y; u0[14]=dq.z; u0[15]=dq.w;
    }
    {
        const float4* p = (const float4*)(ub + (size_t)(tid + 512) * (O_ * D_));
        float4 a = p[0], bq = p[1], c = p[2], dq = p[3];
        u1[0]=a.x; u1[1]=a.y; u1[2]=a.z; u1[3]=a.w;
        u1[4]=bq.x; u1[5]=bq.y; u1[6]=bq.z; u1[7]=bq.w;
        u1[8]=c.x; u1[9]=c.y; u1[10]=c.z; u1[11]=c.w;
        u1[12]=dq.x; u1[13]=dq.y; u1[14]=dq.z; u1[15]=dq.w;
    }
    if (has3) {
        const float4* p = (const float4*)(ub + (size_t)(tid + 1024) * (O_ * D_));
        float4 a = p[0], bq = p[1], c = p[2], dq = p[3];
        u2[0]=a.x; u2[1]=a.y; u2[2]=a.z; u2[3]=a.w;
        u2[4]=bq.x; u2[5]=bq.y; u2[6]=bq.z; u2[7]=bq.w;
        u2[8]=c.x; u2[9]=c.y; u2[10]=c.z; u2[11]=c.w;
        u2[12]=dq.x; u2[13]=dq.y; u2[14]=dq.z; u2[15]=dq.w;
    } else {
        #pragma unroll
        for (int d = 0; d < D_; ++d) u2[d] = 0.f;
    }
    __syncthreads();   // rowmask zeroed

    // --- scatter: per-row 10-bit hypothesis membership ---
    const int* sb = sidx + (size_t)b * (S_ * O_ * H_) + o * H_;
    for (int j = tid; j < S_ * H_; j += NT) {
        int s = j / H_;
        int h = j - s * H_;
        int idx = sb[s * (O_ * H_) + h];
        atomicOr(&rowmask[idx], 1u << h);
    }
    __syncthreads();

    const unsigned rm0 = rowmask[tid];
    const unsigned rm1 = rowmask[tid + 512];
    const unsigned rm2 = has3 ? rowmask[tid + 1024] : 0u;

    float vn0, vn1, vn2;
    {
        float s0 = 0.f, s1 = 0.f, s2 = 0.f;
        #pragma unroll
        for (int d = 0; d < D_; ++d) {
            s0 = fmaf(u0[d], u0[d], s0);
            s1 = fmaf(u1[d], u1[d], s1);
            s2 = fmaf(u2[d], u2[d], s2);
        }
        vn0 = sqrtf(s0); vn1 = sqrtf(s1); vn2 = sqrtf(s2);
    }

    // --- 5 h-pair phases: acc[0..16]=h0 num/den, acc[17..33]=h1 ---
    #pragma unroll 1
    for (int p = 0; p < 5; ++p) {
        const int h0 = 2 * p;
        float acc[34];
        #pragma unroll
        for (int v = 0; v < 34; ++v) acc[v] = 0.f;

        {
            unsigned m = rm0 >> h0;
            float w0 = (m & 1u) ? vn0 : 0.f;
            float w1 = (m & 2u) ? vn0 : 0.f;
            #pragma unroll
            for (int d = 0; d < D_; ++d) {
                acc[d]      = fmaf(w0, u0[d], acc[d]);
                acc[17 + d] = fmaf(w1, u0[d], acc[17 + d]);
            }
            acc[16] += w0; acc[33] += w1;
        }
        {
            unsigned m = rm1 >> h0;
            float w0 = (m & 1u) ? vn1 : 0.f;
            float w1 = (m & 2u) ? vn1 : 0.f;
            #pragma unroll
            for (int d = 0; d < D_; ++d) {
                acc[d]      = fmaf(w0, u1[d], acc[d]);
                acc[17 + d] = fmaf(w1, u1[d], acc[17 + d]);
            }
            acc[16] += w0; acc[33] += w1;
        }
        if (has3) {
            unsigned m = rm2 >> h0;
            float w0 = (m & 1u) ? vn2 : 0.f;
            float w1 = (m & 2u) ? vn2 : 0.f;
            #pragma unroll
            for (int d = 0; d < D_; ++d) {
                acc[d]      = fmaf(w0, u2[d], acc[d]);
                acc[17 + d] = fmaf(w1, u2[d], acc[17 + d]);
            }
            acc[16] += w0; acc[33] += w1;
        }

        #pragma unroll
        for (int v = 0; v < 34; ++v) acc[v] = wave_sum_f32(acc[v]);
        if (lane == 63) {
            #pragma unroll
            for (int v = 0; v < 34; ++v) red[wv][v] = acc[v];
        }
        __syncthreads();

        if (tid < 34) {
            const int p2 = tid / 17, e = tid - 17 * p2;
            float s = 0.f;
            #pragma unroll
            for (int w = 0; w < 8; ++w) s += red[w][tid];
            if (e < 16) {
                float den = 0.f;
                #pragma unroll
                for (int w = 0; w < 8; ++w) den += red[w][p2 * 17 + 16];
                muL[h0 + p2][e] = s / den;
            }
        }
        __syncthreads();   // muL written; red reusable next phase
    }

    // --- loss phase: all rows (registers) vs each mu (LDS, h-loop reused) ---
    const float usq0 = vn0 * vn0, usq1 = vn1 * vn1, usq2 = vn2 * vn2;
    #pragma unroll 1
    for (int h = 0; h < H_; ++h) {
        float mh[D_];
        {
            float4 a = *(const float4*)&muL[h][0];
            float4 bq = *(const float4*)&muL[h][4];
            float4 c = *(const float4*)&muL[h][8];
            float4 dq = *(const float4*)&muL[h][12];
            mh[0]=a.x; mh[1]=a.y; mh[2]=a.z; mh[3]=a.w;
            mh[4]=bq.x; mh[5]=bq.y; mh[6]=bq.z; mh[7]=bq.w;
            mh[8]=c.x; mh[9]=c.y; mh[10]=c.z; mh[11]=c.w;
            mh[12]=dq.x; mh[13]=dq.y; mh[14]=dq.z; mh[15]=dq.w;
        }
        float musq = 0.f;
        #pragma unroll
        for (int d = 0; d < D_; ++d) musq = fmaf(mh[d], mh[d], musq);

        float dot0 = 0.f, dot1 = 0.f, dot2 = 0.f;
        #pragma unroll
        for (int d = 0; d < D_; ++d) {
            dot0 = fmaf(u0[d], mh[d], dot0);
            dot1 = fmaf(u1[d], mh[d], dot1);
            dot2 = fmaf(u2[d], mh[d], dot2);
        }
        float d20 = fmaf(-2.f, dot0, usq0 + musq);
        float d21 = fmaf(-2.f, dot1, usq1 + musq);
        float d22 = fmaf(-2.f, dot2, usq2 + musq);
        double lacc = (double)sqrtf(fmaxf(d20, 0.f))
                    + (double)sqrtf(fmaxf(d21, 0.f));
        if (has3) lacc += (double)sqrtf(fmaxf(d22, 0.f));

        lacc = wave_sum_f64(lacc);
        if (lane == 63) lred[h][wv] = lacc;
    }
    __syncthreads();

    if (tid < H_) {
        double t = 0.0;
        #pragma unroll
        for (int w = 0; w < 8; ++w) t += lred[tid][w];
        losses[tid] = t;
    }
    __syncthreads();
    if (tid == 0) {
        int best = 0; double bl = losses[0];
        #pragma unroll
        for (int h = 1; h < H_; ++h)
            if (losses[h] < bl) { bl = losses[h]; best = h; }
        hstar = best;
    }
    __syncthreads();
    if (tid < D_)
        out[(size_t)bo * D_ + tid] = muL[hstar][tid];
}

extern "C" void kernel_launch(void* const* d_in, const int* in_sizes, int n_in,
                              void* d_out, int out_size, void* d_ws, size_t ws_size,
                              hipStream_t stream) {
    const float* up   = (const float*)d_in[0];
    const int*   sidx = (const int*)d_in[1];
    float*       out  = (float*)d_out;
    ransac_one<<<B_ * O_, NT, 0, stream>>>(up, sidx, out);
}